// Round 4
// baseline (430.693 us; speedup 1.0000x reference)
//
#include <hip/hip_runtime.h>
#include <math.h>

// CRF NLL: out[b] = logZ[b] - gold[b].  B=1024, L=512, T=64.
//
// R4: MFMA-carried recurrence. One wave = 16 chains (n = lane&15), q = lane>>4.
//   q'[j, n] = (sum_i E[i][j] * q[i, n]) * X[j, n]
// as D = A*B with mfma_f32_16x16x32_bf16:
//   A[m][k] = exp(trans[in=32c+8q+j][out=16b+m]) -- FIXED, 8 frags in VGPRs
//   B[k][n] = q (chain n, in-tag k=8q+j per chunk c)
//   D[m][n]: lane holds chain n=lane&15, tags 16b+4q+reg  (m89-verified layout)
// D->B between steps is a 32 B/lane LDS hop (4x ds_write_b64 + 2x ds_read_b128)
// instead of R3's 256 B/lane broadcast (~850 cyc/step -> ~230 cyc/16 chain-steps).
// Emissions exp'd off-chain (4-step pipeline); renorm by power-of-2 every 4 steps.

#define TDIM 64
typedef short bf16x8 __attribute__((ext_vector_type(8)));   // MFMA A/B frag (8 bf16)
typedef float f32x4  __attribute__((ext_vector_type(4)));   // MFMA C/D frag

__device__ __forceinline__ unsigned pack_bf16_trunc(float a, float b) {
    // (hi16(b) << 16) | hi16(a) in one v_perm
    return __builtin_amdgcn_perm(__float_as_uint(b), __float_as_uint(a), 0x07060302u);
}
__device__ __forceinline__ short to_bf16_rne(float x) {
    unsigned u = __float_as_uint(x);
    return (short)((u + 0x7fffu + ((u >> 16) & 1u)) >> 16);
}

__global__ __launch_bounds__(64, 1) void crf_mfma_kernel(
    const float* __restrict__ logits,  // [B, L, 64]
    const int*   __restrict__ tags,    // [B, L]
    const int*   __restrict__ mask,    // [B, L]
    const float* __restrict__ trans,   // [64, 64]
    float* __restrict__ out,           // [B]
    int L)
{
    const int lane = threadIdx.x;
    const int n    = lane & 15;        // local chain (column of D/B)
    const int q    = lane >> 4;        // quad
    const int bg   = blockIdx.x * 16 + n;

    // row stride 72 shorts (144 B): b128 reads 16B-aligned, b64 writes 8B-aligned
    __shared__ unsigned short Qs[16 * 72];

    const float* lb = logits + (size_t)bg * L * TDIM;
    const int*   tb = tags + (size_t)bg * L;
    const int*   mb = mask + (size_t)bg * L;

    // ---------------- gold path score: 4 quads stride t by 4 ----------------
    float g = 0.f;
    for (int t = q; t < L; t += 4) {
        int   tag = tb[t];
        float mk  = (float)mb[t];
        float em  = lb[(size_t)t * TDIM + tag] * mk;
        float tr  = (t > 0) ? trans[tb[t - 1] * TDIM + tag] * mk : 0.f;
        g += em + tr;
    }
    g += __shfl_xor(g, 16);
    g += __shfl_xor(g, 32);   // all 4 lanes of column n hold gold[bg]

    // ------------- A fragments: exp(trans)^T blocks, bf16, fixed -------------
    bf16x8 Af[4][2];
    #pragma unroll
    for (int bb = 0; bb < 4; ++bb)
        #pragma unroll
        for (int c = 0; c < 2; ++c)
            #pragma unroll
            for (int jj = 0; jj < 8; ++jj)
                Af[bb][c][jj] = to_bf16_rne(
                    __expf(trans[(32 * c + 8 * q + jj) * TDIM + 16 * bb + n]));

    // ------------- init q from alpha0 (D-layout positions) -------------
    f32x4 a0[4];
    #pragma unroll
    for (int bb = 0; bb < 4; ++bb)
        a0[bb] = *(const f32x4*)(lb + 16 * bb + 4 * q);
    float base = a0[0][0];
    #pragma unroll
    for (int bb = 0; bb < 4; ++bb)
        #pragma unroll
        for (int r = 0; r < 4; ++r) base = fmaxf(base, a0[bb][r]);
    base = fmaxf(base, __shfl_xor(base, 16));
    base = fmaxf(base, __shfl_xor(base, 32));   // per-chain max (uniform per column)

    float qv[16];
    #pragma unroll
    for (int bb = 0; bb < 4; ++bb)
        #pragma unroll
        for (int r = 0; r < 4; ++r) qv[4 * bb + r] = __expf(a0[bb][r] - base);
    int kacc = 0;

    // ------------- emission pipeline (blocks of 4 steps) -------------
    f32x4 R[4][4];   // raw emissions for next block (in flight)
    f32x4 E[4][4];   // exp'd emissions for current block
    #pragma unroll
    for (int s = 0; s < 4; ++s)
        #pragma unroll
        for (int bb = 0; bb < 4; ++bb)
            R[s][bb] = *(const f32x4*)(lb + (size_t)s * TDIM + 16 * bb + 4 * q);
    int4 Mc = *(const int4*)(mb);   // masks t=0..3 (t=0 overridden below)

    const int NBK = L >> 2;
    for (int kb = 0; kb < NBK; ++kb) {
        // exp current block's emissions (loads issued last block -> landed)
        #pragma unroll
        for (int s = 0; s < 4; ++s)
            #pragma unroll
            for (int bb = 0; bb < 4; ++bb)
                #pragma unroll
                for (int r = 0; r < 4; ++r)
                    E[s][bb][r] = __expf(R[s][bb][r]);

        // issue next block's loads
        const int kn = (kb + 1 < NBK) ? kb + 1 : kb;
        #pragma unroll
        for (int s = 0; s < 4; ++s)
            #pragma unroll
            for (int bb = 0; bb < 4; ++bb)
                R[s][bb] = *(const f32x4*)(lb + (size_t)(4 * kn + s) * TDIM + 16 * bb + 4 * q);
        int4 Mn = *(const int4*)(mb + 4 * kn);

        const int mstep[4] = {(kb == 0) ? 0 : Mc.x, Mc.y, Mc.z, Mc.w};

        #pragma unroll
        for (int s = 0; s < 4; ++s) {
            // ---- D-positions -> bf16 -> LDS (tags contiguous per chain row) ----
            #pragma unroll
            for (int bb = 0; bb < 4; ++bb) {
                uint2 w;
                w.x = pack_bf16_trunc(qv[4 * bb + 0], qv[4 * bb + 1]);
                w.y = pack_bf16_trunc(qv[4 * bb + 2], qv[4 * bb + 3]);
                *(uint2*)&Qs[n * 72 + 16 * bb + 4 * q] = w;   // tags 16bb+4q..+3
            }
            __builtin_amdgcn_wave_barrier();
            bf16x8 B0 = *(const bf16x8*)&Qs[n * 72 + 8 * q];       // k = 8q..8q+7
            bf16x8 B1 = *(const bf16x8*)&Qs[n * 72 + 32 + 8 * q];  // k = 32+8q..+7
            __builtin_amdgcn_wave_barrier();

            // ---- MFMA: D = E^T * q, then scale by exp(emission) ----
            const f32x4 zero = {0.f, 0.f, 0.f, 0.f};
            float nv[16];
            #pragma unroll
            for (int bb = 0; bb < 4; ++bb) {
                f32x4 acc = __builtin_amdgcn_mfma_f32_16x16x32_bf16(Af[bb][0], B0, zero, 0, 0, 0);
                acc = __builtin_amdgcn_mfma_f32_16x16x32_bf16(Af[bb][1], B1, acc, 0, 0, 0);
                #pragma unroll
                for (int r = 0; r < 4; ++r)
                    nv[4 * bb + r] = acc[r] * E[s][bb][r];
            }
            const int mk = mstep[s];
            #pragma unroll
            for (int i = 0; i < 16; ++i)
                qv[i] = (mk > 0) ? nv[i] : qv[i];

            // ---- power-of-2 renorm once per block (growth <= e^44 in 4 steps) ----
            if (s == 3) {
                float mx = qv[0];
                #pragma unroll
                for (int i = 1; i < 16; ++i) mx = fmaxf(mx, qv[i]);
                mx = fmaxf(mx, __shfl_xor(mx, 16));
                mx = fmaxf(mx, __shfl_xor(mx, 32));
                int kk = (int)((__float_as_uint(mx) >> 23) & 0xffu) - 127;
                kacc += kk;
                float sc = __uint_as_float((unsigned)(127 - kk) << 23);
                #pragma unroll
                for (int i = 0; i < 16; ++i) qv[i] *= sc;
            }
        }
        Mc = Mn;
    }

    // ---------------- final logsumexp per chain + output ----------------
    float ssum = 0.f;
    #pragma unroll
    for (int i = 0; i < 16; ++i) ssum += qv[i];
    ssum += __shfl_xor(ssum, 16);
    ssum += __shfl_xor(ssum, 32);
    float logZ = base + (float)kacc * 0.6931471805599453f + __logf(ssum);

    if (lane < 16) out[blockIdx.x * 16 + n] = logZ - g;
}

extern "C" void kernel_launch(void* const* d_in, const int* in_sizes, int n_in,
                              void* d_out, int out_size, void* d_ws, size_t ws_size,
                              hipStream_t stream) {
    const float* logits = (const float*)d_in[0];
    const int*   tags   = (const int*)d_in[1];
    const int*   mask   = (const int*)d_in[2];
    const float* trans  = (const float*)d_in[3];
    float* out = (float*)d_out;

    const int B = out_size;            // 1024
    const int L = in_sizes[1] / B;     // 512 (multiple of 4)

    crf_mfma_kernel<<<B / 16, 64, 0, stream>>>(logits, tags, mask, trans, out, L);
}

// Round 5
// 256.095 us; speedup vs baseline: 1.6818x; 1.6818x over previous
//
#include <hip/hip_runtime.h>
#include <math.h>

// CRF NLL: out[b] = logZ[b] - gold[b].  B=1024, L=512, T=64 (lane j <-> tag j).
//
// R5: (a) exact fwd/bwd split: logZ = log(z^T y), y = fwd state after pos 255,
//     z^T = 1^T Op_511..Op_256 run BACKWARD (z' = E*(X_t.*z)) from ones.
//     2048 independent 256-step chains -> 2 waves/SIMD -> mutual latency hiding.
//     (b) f16 state: 1 ds_write_b16 + 8 ds_read_b128 per step (was 16 reads),
//     dot via v_dot2_f32_f16 (32 instrs). Renorm centers lane0 at 2^-10 so the
//     +-14-nat tag spread fits f16 range; kacc (integer log2 scale) fixes logZ.

#define TDIM 64
typedef _Float16 h16;
typedef _Float16 v2h __attribute__((ext_vector_type(2)));

union H8 { float4 f4; v2h h[4]; };

#if defined(__has_builtin)
#if __has_builtin(__builtin_amdgcn_fdot2)
#define HAVE_FDOT2 1
#endif
#endif

__device__ __forceinline__ float dot2acc(v2h a, v2h b, float c) {
#ifdef HAVE_FDOT2
    return __builtin_amdgcn_fdot2(a, b, c, false);
#else
    return c + (float)a[0] * (float)b[0] + (float)a[1] * (float)b[1];
#endif
}

// power-of-2 renorm: scale v so lane0's exponent becomes 2^-10; kacc += k
__device__ __forceinline__ float renorm(float v, int& kacc) {
    int rf = __builtin_amdgcn_readfirstlane(__float_as_int(v));
    int kk = ((rf >> 23) & 0xff) - 127 + 10;
    kacc += kk;
    return v * __uint_as_float((unsigned)(127 - kk) << 23);
}

__global__ __launch_bounds__(128, 1) void crf_fb_kernel(
    const float* __restrict__ logits,  // [B, L, 64]
    const int*   __restrict__ tags,    // [B, L]
    const int*   __restrict__ mask,    // [B, L]
    const float* __restrict__ trans,   // [64, 64]
    float* __restrict__ out,           // [B]
    int L)
{
    const int tid = threadIdx.x;
    const int w   = tid >> 6;          // 0 = forward, 1 = backward
    const int j   = tid & 63;          // lane = tag index
    const int b   = blockIdx.x;
    const int H   = L >> 1;            // split point (256)

    __shared__ __align__(16) h16   Qs[2][TDIM];     // per-wave state buffer
    __shared__ __align__(16) int   smask[512];
    __shared__ __align__(16) float comb[2][TDIM];   // final combine
    __shared__ float gpart[2];
    __shared__ float bpart[2];
    __shared__ int   kpart[2];

    const float* lb = logits + (size_t)b * L * TDIM;
    const int*   tb = tags + (size_t)b * L;
    const int*   mb = mask + (size_t)b * L;

    // ---- stage mask (128 threads x int4 = 512), force mask[0]=0 ----
    ((int4*)smask)[tid] = ((const int4*)mb)[tid];
    if (tid == 0) smask[0] = 0;
    __syncthreads();

    // ---- gold score: this wave's half of positions ----
    float g = 0.f;
    for (int t = w * H + j; t < (w + 1) * H; t += 64) {
        int   tag = tb[t];
        float mk  = (float)mb[t];
        float em  = lb[(size_t)t * TDIM + tag] * mk;
        float tr  = (t > 0) ? trans[tb[t - 1] * TDIM + tag] * mk : 0.f;
        g += em + tr;
    }
    #pragma unroll
    for (int o = 32; o >= 1; o >>= 1) g += __shfl_xor(g, o);

    // ---- E fragment: fwd lane j holds COLUMN j (exp(trans[i][j])),
    //                  bwd lane i holds ROW i (exp(trans[i][jj])) ----
    v2h epk[32];
    #pragma unroll
    for (int p = 0; p < 32; ++p) {
        float a, c;
        if (w == 0) { a = __expf(trans[(2 * p) * TDIM + j]);
                      c = __expf(trans[(2 * p + 1) * TDIM + j]); }
        else        { a = __expf(trans[j * TDIM + 2 * p]);
                      c = __expf(trans[j * TDIM + 2 * p + 1]); }
        v2h t2 = {(h16)a, (h16)c};
        epk[p] = t2;
    }

    int kacc = 0;
    float base, q;
    h16* myQ = Qs[w];

    if (w == 0) {
        // ---------------- FORWARD: init at pos 0, steps t=0..H-1 ----------
        float a0 = lb[j];
        base = __int_as_float(__builtin_amdgcn_readfirstlane(__float_as_int(a0)));
        q = renorm(__expf(a0 - base), kacc);
        myQ[j] = (h16)q;

        float R[8], X[8];
        #pragma unroll
        for (int u = 0; u < 8; ++u) R[u] = lb[(size_t)u * TDIM + j];

        const int NB = H >> 3;
        for (int kb = 0; kb < NB; ++kb) {
            #pragma unroll
            for (int u = 0; u < 8; ++u) X[u] = __expf(R[u]);
            const int kn = (kb + 1 < NB) ? kb + 1 : kb;
            #pragma unroll
            for (int u = 0; u < 8; ++u)
                R[u] = lb[(size_t)(8 * kn + u) * TDIM + j];
            int4 mc0 = ((const int4*)smask)[kb * 2];
            int4 mc1 = ((const int4*)smask)[kb * 2 + 1];
            const int mks[8] = {mc0.x, mc0.y, mc0.z, mc0.w,
                                mc1.x, mc1.y, mc1.z, mc1.w};
            #pragma unroll
            for (int u = 0; u < 8; ++u) {
                __builtin_amdgcn_wave_barrier();
                const H8* pv = (const H8*)myQ;
                float a0s = 0.f, a1s = 0.f, a2s = 0.f, a3s = 0.f;
                #pragma unroll
                for (int i = 0; i < 8; ++i) {
                    H8 f = pv[i];                       // LDS broadcast
                    a0s = dot2acc(f.h[0], epk[4 * i + 0], a0s);
                    a1s = dot2acc(f.h[1], epk[4 * i + 1], a1s);
                    a2s = dot2acc(f.h[2], epk[4 * i + 2], a2s);
                    a3s = dot2acc(f.h[3], epk[4 * i + 3], a3s);
                }
                float s = (a0s + a1s) + (a2s + a3s);
                float q1 = s * X[u];
                q1 = (mks[u] > 0) ? q1 : q;
                q = renorm(q1, kacc);
                myQ[j] = (h16)q;
                __builtin_amdgcn_wave_barrier();
            }
        }
    } else {
        // ---------------- BACKWARD: z=1, steps t=L-1 down to H ------------
        base = 0.f;
        q = 1.f;

        float R[8], X[8];
        #pragma unroll
        for (int u = 0; u < 8; ++u)
            R[u] = lb[(size_t)(L - 1 - u) * TDIM + j];

        const int NB = H >> 3;
        for (int kb = 0; kb < NB; ++kb) {
            #pragma unroll
            for (int u = 0; u < 8; ++u) X[u] = __expf(R[u]);
            const int kn = (kb + 1 < NB) ? kb + 1 : kb;
            #pragma unroll
            for (int u = 0; u < 8; ++u)
                R[u] = lb[(size_t)(L - 1 - 8 * kn - u) * TDIM + j];
            int mks[8];
            #pragma unroll
            for (int u = 0; u < 8; ++u) mks[u] = smask[L - 1 - 8 * kb - u];
            #pragma unroll
            for (int u = 0; u < 8; ++u) {
                // u_j = z_j * X_t[j]; write; read-all; z'_i = dot(Erow_i, u)
                float uv = q * X[u];
                myQ[j] = (h16)uv;
                __builtin_amdgcn_wave_barrier();
                const H8* pv = (const H8*)myQ;
                float a0s = 0.f, a1s = 0.f, a2s = 0.f, a3s = 0.f;
                #pragma unroll
                for (int i = 0; i < 8; ++i) {
                    H8 f = pv[i];
                    a0s = dot2acc(f.h[0], epk[4 * i + 0], a0s);
                    a1s = dot2acc(f.h[1], epk[4 * i + 1], a1s);
                    a2s = dot2acc(f.h[2], epk[4 * i + 2], a2s);
                    a3s = dot2acc(f.h[3], epk[4 * i + 3], a3s);
                }
                float s = (a0s + a1s) + (a2s + a3s);
                float z1 = (mks[u] > 0) ? s : q;
                q = renorm(z1, kacc);
                __builtin_amdgcn_wave_barrier();
            }
        }
    }

    // ---------------- combine: logZ = base + (Kf+Kb)ln2 + log(sum q_f*q_b) --
    comb[w][j] = q;
    if (j == 0) { gpart[w] = g; bpart[w] = base; kpart[w] = kacc; }
    __syncthreads();

    if (tid < 64) {
        float prod = comb[0][j] * comb[1][j];
        #pragma unroll
        for (int o = 32; o >= 1; o >>= 1) prod += __shfl_xor(prod, o);
        if (j == 0) {
            float logZ = bpart[0] + bpart[1]
                       + (float)(kpart[0] + kpart[1]) * 0.6931471805599453f
                       + __logf(prod);
            out[b] = logZ - (gpart[0] + gpart[1]);
        }
    }
}

extern "C" void kernel_launch(void* const* d_in, const int* in_sizes, int n_in,
                              void* d_out, int out_size, void* d_ws, size_t ws_size,
                              hipStream_t stream) {
    const float* logits = (const float*)d_in[0];
    const int*   tags   = (const int*)d_in[1];
    const int*   mask   = (const int*)d_in[2];
    const float* trans  = (const float*)d_in[3];
    float* out = (float*)d_out;

    const int B = out_size;            // 1024
    const int L = in_sizes[1] / B;     // 512 (even; halves multiple of 8)

    crf_fb_kernel<<<B, 128, 0, stream>>>(logits, tags, mask, trans, out, L);
}

// Round 6
// 245.787 us; speedup vs baseline: 1.7523x; 1.0419x over previous
//
#include <hip/hip_runtime.h>
#include <math.h>

// CRF NLL: out[b] = logZ[b] - gold[b].  B=1024, L=512, T=64 (lane j <-> tag j).
//
// R5 (120 us kernel): exact fwd/bwd split (2 waves/block, 256 steps each,
//   combine logZ = log(z^T y)); f16 state (1 ds_write_b16 + 8 ds_read_b128 per
//   step); power-of-2 renorm (no transcendental on the chain).
// R6: rocprof showed 1125 cyc/step, VALUBusy 36%, VGPR=60 -> compiler
//   serialized the 8 LDS reads (read->wait->dot->read...: ~8x120 cyc).
//   Fix: explicit load-all-then-compute (8 H8 frags in regs -> 8 reads in
//   flight, last lands ~216 cyc) + 8 short dot chains (4 deps each) instead
//   of 4 chains x 8 deps.

#define TDIM 64
typedef _Float16 h16;
typedef _Float16 v2h __attribute__((ext_vector_type(2)));

union H8 { float4 f4; v2h h[4]; };

#if defined(__has_builtin)
#if __has_builtin(__builtin_amdgcn_fdot2)
#define HAVE_FDOT2 1
#endif
#endif

__device__ __forceinline__ float dot2acc(v2h a, v2h b, float c) {
#ifdef HAVE_FDOT2
    return __builtin_amdgcn_fdot2(a, b, c, false);
#else
    return c + (float)a[0] * (float)b[0] + (float)a[1] * (float)b[1];
#endif
}

// power-of-2 renorm: scale v so lane0's exponent becomes 2^-10; kacc += k
__device__ __forceinline__ float renorm(float v, int& kacc) {
    int rf = __builtin_amdgcn_readfirstlane(__float_as_int(v));
    int kk = ((rf >> 23) & 0xff) - 127 + 10;
    kacc += kk;
    return v * __uint_as_float((unsigned)(127 - kk) << 23);
}

// one recurrence step's all-to-all: q_vec (in LDS) -> dot with epk -> s
__device__ __forceinline__ float step_dot(const h16* myQ, const v2h* epk) {
    const H8* pv = (const H8*)myQ;
    H8 f[8];
    #pragma unroll
    for (int i = 0; i < 8; ++i) f[i] = pv[i];   // 8 b128 reads in flight
    float acc[8];
    #pragma unroll
    for (int i = 0; i < 8; ++i) {
        float a = dot2acc(f[i].h[0], epk[4 * i + 0], 0.f);
        a = dot2acc(f[i].h[1], epk[4 * i + 1], a);
        a = dot2acc(f[i].h[2], epk[4 * i + 2], a);
        a = dot2acc(f[i].h[3], epk[4 * i + 3], a);
        acc[i] = a;
    }
    float s01 = acc[0] + acc[1], s23 = acc[2] + acc[3];
    float s45 = acc[4] + acc[5], s67 = acc[6] + acc[7];
    return ((s01 + s23) + (s45 + s67));
}

__global__ __launch_bounds__(128, 1) void crf_fb_kernel(
    const float* __restrict__ logits,  // [B, L, 64]
    const int*   __restrict__ tags,    // [B, L]
    const int*   __restrict__ mask,    // [B, L]
    const float* __restrict__ trans,   // [64, 64]
    float* __restrict__ out,           // [B]
    int L)
{
    const int tid = threadIdx.x;
    const int w   = tid >> 6;          // 0 = forward, 1 = backward
    const int j   = tid & 63;          // lane = tag index
    const int b   = blockIdx.x;
    const int H   = L >> 1;            // split point (256)

    __shared__ __align__(16) h16   Qs[2][TDIM];     // per-wave state buffer
    __shared__ __align__(16) int   smask[512];
    __shared__ __align__(16) float comb[2][TDIM];   // final combine
    __shared__ float gpart[2];
    __shared__ float bpart[2];
    __shared__ int   kpart[2];

    const float* lb = logits + (size_t)b * L * TDIM;
    const int*   tb = tags + (size_t)b * L;
    const int*   mb = mask + (size_t)b * L;

    // ---- stage mask (128 threads x int4 = 512), force mask[0]=0 ----
    ((int4*)smask)[tid] = ((const int4*)mb)[tid];
    if (tid == 0) smask[0] = 0;
    __syncthreads();

    // ---- gold score: this wave's half of positions ----
    float g = 0.f;
    for (int t = w * H + j; t < (w + 1) * H; t += 64) {
        int   tag = tb[t];
        float mk  = (float)mb[t];
        float em  = lb[(size_t)t * TDIM + tag] * mk;
        float tr  = (t > 0) ? trans[tb[t - 1] * TDIM + tag] * mk : 0.f;
        g += em + tr;
    }
    #pragma unroll
    for (int o = 32; o >= 1; o >>= 1) g += __shfl_xor(g, o);

    // ---- E fragment: fwd lane j holds COLUMN j (exp(trans[i][j])),
    //                  bwd lane i holds ROW i (exp(trans[i][jj])) ----
    v2h epk[32];
    #pragma unroll
    for (int p = 0; p < 32; ++p) {
        float a, c;
        if (w == 0) { a = __expf(trans[(2 * p) * TDIM + j]);
                      c = __expf(trans[(2 * p + 1) * TDIM + j]); }
        else        { a = __expf(trans[j * TDIM + 2 * p]);
                      c = __expf(trans[j * TDIM + 2 * p + 1]); }
        v2h t2 = {(h16)a, (h16)c};
        epk[p] = t2;
    }

    int kacc = 0;
    float base, q;
    h16* myQ = Qs[w];

    if (w == 0) {
        // ---------------- FORWARD: init at pos 0, steps t=0..H-1 ----------
        float a0 = lb[j];
        base = __int_as_float(__builtin_amdgcn_readfirstlane(__float_as_int(a0)));
        q = renorm(__expf(a0 - base), kacc);
        myQ[j] = (h16)q;

        float R[8], X[8];
        #pragma unroll
        for (int u = 0; u < 8; ++u) R[u] = lb[(size_t)u * TDIM + j];

        const int NB = H >> 3;
        for (int kb = 0; kb < NB; ++kb) {
            #pragma unroll
            for (int u = 0; u < 8; ++u) X[u] = __expf(R[u]);
            const int kn = (kb + 1 < NB) ? kb + 1 : kb;
            #pragma unroll
            for (int u = 0; u < 8; ++u)
                R[u] = lb[(size_t)(8 * kn + u) * TDIM + j];
            int4 mc0 = ((const int4*)smask)[kb * 2];
            int4 mc1 = ((const int4*)smask)[kb * 2 + 1];
            const int mks[8] = {mc0.x, mc0.y, mc0.z, mc0.w,
                                mc1.x, mc1.y, mc1.z, mc1.w};
            #pragma unroll
            for (int u = 0; u < 8; ++u) {
                __builtin_amdgcn_wave_barrier();
                float s = step_dot(myQ, epk);
                float q1 = s * X[u];
                q1 = (mks[u] > 0) ? q1 : q;
                q = renorm(q1, kacc);
                myQ[j] = (h16)q;
                __builtin_amdgcn_wave_barrier();
            }
        }
    } else {
        // ---------------- BACKWARD: z=1, steps t=L-1 down to H ------------
        base = 0.f;
        q = 1.f;

        float R[8], X[8];
        #pragma unroll
        for (int u = 0; u < 8; ++u)
            R[u] = lb[(size_t)(L - 1 - u) * TDIM + j];

        const int NB = H >> 3;
        for (int kb = 0; kb < NB; ++kb) {
            #pragma unroll
            for (int u = 0; u < 8; ++u) X[u] = __expf(R[u]);
            const int kn = (kb + 1 < NB) ? kb + 1 : kb;
            #pragma unroll
            for (int u = 0; u < 8; ++u)
                R[u] = lb[(size_t)(L - 1 - 8 * kn - u) * TDIM + j];
            int mks[8];
            #pragma unroll
            for (int u = 0; u < 8; ++u) mks[u] = smask[L - 1 - 8 * kb - u];
            #pragma unroll
            for (int u = 0; u < 8; ++u) {
                // u_j = z_j * X_t[j]; write; read-all; z'_i = dot(Erow_i, u)
                float uv = q * X[u];
                myQ[j] = (h16)uv;
                __builtin_amdgcn_wave_barrier();
                float s = step_dot(myQ, epk);
                float z1 = (mks[u] > 0) ? s : q;
                q = renorm(z1, kacc);
                __builtin_amdgcn_wave_barrier();
            }
        }
    }

    // ---------------- combine: logZ = base + (Kf+Kb)ln2 + log(sum q_f*q_b) --
    comb[w][j] = q;
    if (j == 0) { gpart[w] = g; bpart[w] = base; kpart[w] = kacc; }
    __syncthreads();

    if (tid < 64) {
        float prod = comb[0][j] * comb[1][j];
        #pragma unroll
        for (int o = 32; o >= 1; o >>= 1) prod += __shfl_xor(prod, o);
        if (j == 0) {
            float logZ = bpart[0] + bpart[1]
                       + (float)(kpart[0] + kpart[1]) * 0.6931471805599453f
                       + __logf(prod);
            out[b] = logZ - (gpart[0] + gpart[1]);
        }
    }
}

extern "C" void kernel_launch(void* const* d_in, const int* in_sizes, int n_in,
                              void* d_out, int out_size, void* d_ws, size_t ws_size,
                              hipStream_t stream) {
    const float* logits = (const float*)d_in[0];
    const int*   tags   = (const int*)d_in[1];
    const int*   mask   = (const int*)d_in[2];
    const float* trans  = (const float*)d_in[3];
    float* out = (float*)d_out;

    const int B = out_size;            // 1024
    const int L = in_sizes[1] / B;     // 512 (even; halves multiple of 8)

    crf_fb_kernel<<<B, 128, 0, stream>>>(logits, tags, mask, trans, out, L);
}